// Round 7
// baseline (261.463 us; speedup 1.0000x reference)
//
#include <hip/hip_runtime.h>
#include <cmath>

#define N_NODES 50000
#define N_EDGES 800000
#define NBUCK 196          // buckets of 256 nodes: bucket = dst >> 8
#define NHB 196            // histogram blocks, 4096 edges each
#define EPB 4096
// IN_DIM = HEADS*HID = 128, HEADS=4, HID=32

typedef unsigned short u16;
typedef unsigned int u32;
typedef __attribute__((ext_vector_type(8))) short bf16x8;
typedef __attribute__((ext_vector_type(4))) float f32x4;

static __device__ __forceinline__ float lrelu(float x) { return x > 0.f ? x : 0.2f * x; }
static __device__ __forceinline__ float bf2f(u16 u) { return __uint_as_float(((u32)u) << 16); }
static __device__ __forceinline__ float bflo(u32 u) { return __uint_as_float(u << 16); }
static __device__ __forceinline__ float bfhi(u32 u) { return __uint_as_float(u & 0xFFFF0000u); }
static __device__ __forceinline__ u16 f2bf(float f) {
    u32 b = __float_as_uint(f);
    return (u16)((b + 0x7FFFu + ((b >> 16) & 1u)) >> 16);  // RNE
}
static __device__ __forceinline__ u32 pack2(float a, float b) {
    return (u32)f2bf(a) | ((u32)f2bf(b) << 16);
}

// ---------------- bucketed CSR build ----------------
__global__ __launch_bounds__(1024) void bhist_k(const int* __restrict__ dst, u32* __restrict__ bcnt) {
    __shared__ u32 hist[NBUCK];
    int tid = threadIdx.x;
    for (int i = tid; i < NBUCK; i += 1024) hist[i] = 0;
    __syncthreads();
    int base = blockIdx.x * EPB;
#pragma unroll
    for (int k = 0; k < 4; ++k) {
        int e = base + k * 1024 + tid;
        if (e < N_EDGES) atomicAdd(&hist[dst[e] >> 8], 1u);
    }
    __syncthreads();
    for (int i = tid; i < NBUCK; i += 1024) bcnt[(size_t)blockIdx.x * NBUCK + i] = hist[i];
}

__global__ __launch_bounds__(256) void bscan_k(const u32* __restrict__ bcnt, u32* __restrict__ wbase,
                                               int* __restrict__ bstart) {
    __shared__ int s[256];
    int t = threadIdx.x;
    u32 run = 0;
    if (t < NBUCK) {
        for (int blk = 0; blk < NHB; ++blk) {
            u32 v = bcnt[(size_t)blk * NBUCK + t];
            wbase[(size_t)blk * NBUCK + t] = run;
            run += v;
        }
    }
    s[t] = (t < NBUCK) ? (int)run : 0;
    __syncthreads();
    for (int o = 1; o < 256; o <<= 1) {
        int v = (t >= o) ? s[t - o] : 0;
        __syncthreads();
        s[t] += v;
        __syncthreads();
    }
    if (t < NBUCK) bstart[t] = (t == 0) ? 0 : s[t - 1];
    if (t == NBUCK - 1) bstart[NBUCK] = s[t];
}

__global__ __launch_bounds__(1024) void bscatter_k(const int* __restrict__ src, const int* __restrict__ dst,
                                                   const u32* __restrict__ wbase, const int* __restrict__ bstart,
                                                   u32* __restrict__ bucketed) {
    __shared__ u32 pos[NBUCK];
    int tid = threadIdx.x;
    for (int i = tid; i < NBUCK; i += 1024)
        pos[i] = (u32)bstart[i] + wbase[(size_t)blockIdx.x * NBUCK + i];
    __syncthreads();
    int base = blockIdx.x * EPB;
#pragma unroll
    for (int k = 0; k < 4; ++k) {
        int e = base + k * 1024 + tid;
        if (e < N_EDGES) {
            int d = dst[e];
            int b = d >> 8;
            u32 p = atomicAdd(&pos[b], 1u);
            bucketed[p] = (u32)src[e] | ((u32)(d & 255) << 16);
        }
    }
}

// per-bucket fine CSR + per-node src-sort (sort = L2-locality optimization for agg;
// overflow (deg>64, astronomically rare for Poisson-16) lands unsorted — still correct)
#define SORTCAP 64
#define SORTSTRIDE 68   // u16 stride; (tid*34 + j/2) % 32 spreads banks across lanes
__global__ __launch_bounds__(256) void bcsr_k(const u32* __restrict__ bucketed, const int* __restrict__ bstart,
                                              int* __restrict__ offs, u16* __restrict__ srcs) {
    __shared__ u32 cnt[256];
    __shared__ int s[256];
    __shared__ int ex[256];
    __shared__ u32 fp[256];
    __shared__ u16 sortbuf[256 * SORTSTRIDE];   // 34.8 KB
    int b = blockIdx.x;
    int tid = threadIdx.x;
    int ebeg = bstart[b], eend = bstart[b + 1];
    int ne = eend - ebeg;
    cnt[tid] = 0;
    __syncthreads();
    for (int i = tid; i < ne; i += 256)
        atomicAdd(&cnt[bucketed[ebeg + i] >> 16], 1u);
    __syncthreads();
    s[tid] = (int)cnt[tid];
    __syncthreads();
    for (int o = 1; o < 256; o <<= 1) {
        int v = (tid >= o) ? s[tid - o] : 0;
        __syncthreads();
        s[tid] += v;
        __syncthreads();
    }
    int excl = s[tid] - (int)cnt[tid];
    ex[tid] = excl;
    fp[tid] = (u32)excl;
    int node = b * 256 + tid;
    if (node < N_NODES) offs[node] = ebeg + excl;
    if (b == NBUCK - 1 && tid == 0) offs[N_NODES] = N_EDGES;
    __syncthreads();
    // scatter into LDS (per-node segments), overflow directly to global
    for (int i = tid; i < ne; i += 256) {
        u32 u = bucketed[ebeg + i];
        int dn = (int)(u >> 16);
        u32 p = atomicAdd(&fp[dn], 1u);
        int local = (int)p - ex[dn];
        if (local < SORTCAP) sortbuf[dn * SORTSTRIDE + local] = (u16)(u & 0xFFFFu);
        else srcs[ebeg + p] = (u16)(u & 0xFFFFu);
    }
    __syncthreads();
    // per-thread insertion sort of its node's segment, then write back
    int deg = (int)cnt[tid];
    int m = deg < SORTCAP ? deg : SORTCAP;
    u16* sb = &sortbuf[tid * SORTSTRIDE];
    for (int i = 1; i < m; ++i) {
        u16 key = sb[i];
        int j = i - 1;
        while (j >= 0 && sb[j] > key) { sb[j + 1] = sb[j]; --j; }
        sb[j + 1] = key;
    }
    int ebase = ebeg + ex[tid];
    for (int i = 0; i < m; ++i) srcs[ebase + i] = sb[i];
}

// ---------------- W pre-pack: both layers in one dispatch ----------------
// Wp[((nt*4+ks)*64+lane)*8+j] = bf16(W[ks*32 + (lane>>4)*8 + j][nt*16 + (lane&15)])
__global__ __launch_bounds__(256) void packW_k(const float* __restrict__ W1, const float* __restrict__ W2,
                                               u16* __restrict__ Wp1, u16* __restrict__ Wp2) {
    int gi = blockIdx.x * 256 + threadIdx.x;
    const float* W = (gi < 16384) ? W1 : W2;
    u16* Wp = (gi < 16384) ? Wp1 : Wp2;
    int i = gi & 16383;
    int j = i & 7, lane = (i >> 3) & 63, ks = (i >> 9) & 3, nt = i >> 11;
    int k = ks * 32 + (lane >> 4) * 8 + j;
    int ncol = nt * 16 + (lane & 15);
    Wp[i] = f2bf(W[k * 128 + ncol]);
}

// ---------------- MFMA GEMM (X[N,128] @ W[128,128]) fused with el/er head dots ----------------
template <int BF16IN>
__global__ __launch_bounds__(256) void gemm_mfma(
    const void* __restrict__ Xv, const u16* __restrict__ Wp,
    const float* __restrict__ al, const float* __restrict__ ar,
    u16* __restrict__ hf, float* __restrict__ el, float* __restrict__ er, int n)
{
    __shared__ u16 xs[64][136];   // +8 pad: row stride 272B -> 2-way LDS bank aliasing (free)
    int row0 = blockIdx.x * 64;
    int tid = threadIdx.x;
    if (BF16IN) {
        const uint4* Xb = (const uint4*)Xv;
        for (int i = tid; i < 1024; i += 256) {
            int r = i >> 4, c = i & 15;
            uint4 v = make_uint4(0u, 0u, 0u, 0u);
            if (row0 + r < n) v = Xb[(size_t)(row0 + r) * 16 + c];
            ((uint4*)&xs[r][0])[c] = v;
        }
    } else {
        const float4* X4 = (const float4*)Xv;
        for (int i = tid; i < 2048; i += 256) {
            int r = i >> 5, c = i & 31;
            float4 v = make_float4(0.f, 0.f, 0.f, 0.f);
            if (row0 + r < n) v = X4[(size_t)(row0 + r) * 32 + c];
            ((uint2*)&xs[r][0])[c] = make_uint2(pack2(v.x, v.y), pack2(v.z, v.w));
        }
    }
    __syncthreads();

    int wave = tid >> 6, lane = tid & 63;
    int quad = lane >> 4, l15 = lane & 15;

    bf16x8 bfrag[2][4];
#pragma unroll
    for (int ct = 0; ct < 2; ++ct) {
        int nt = wave * 2 + ct;
#pragma unroll
        for (int ks = 0; ks < 4; ++ks)
            bfrag[ct][ks] = *(const bf16x8*)(Wp + ((((nt * 4 + ks) * 64) + lane) << 3));
    }

    f32x4 acc[4][2];
#pragma unroll
    for (int rt = 0; rt < 4; ++rt)
#pragma unroll
        for (int ct = 0; ct < 2; ++ct)
            acc[rt][ct] = (f32x4){0.f, 0.f, 0.f, 0.f};

#pragma unroll
    for (int ks = 0; ks < 4; ++ks) {
#pragma unroll
        for (int rt = 0; rt < 4; ++rt) {
            bf16x8 a = *(const bf16x8*)&xs[rt * 16 + l15][ks * 32 + quad * 8];
            acc[rt][0] = __builtin_amdgcn_mfma_f32_16x16x32_bf16(a, bfrag[0][ks], acc[rt][0], 0, 0, 0);
            acc[rt][1] = __builtin_amdgcn_mfma_f32_16x16x32_bf16(a, bfrag[1][ks], acc[rt][1], 0, 0, 0);
        }
    }

    float alv0 = al[wave * 32 + l15], alv1 = al[wave * 32 + 16 + l15];
    float arv0 = ar[wave * 32 + l15], arv1 = ar[wave * 32 + 16 + l15];
#pragma unroll
    for (int rt = 0; rt < 4; ++rt) {
#pragma unroll
        for (int r = 0; r < 4; ++r) {
            int row = row0 + rt * 16 + quad * 4 + r;
            float c0 = acc[rt][0][r], c1 = acc[rt][1][r];
            if (row < n) {
                hf[(size_t)row * 128 + wave * 32 + l15] = f2bf(c0);
                hf[(size_t)row * 128 + wave * 32 + 16 + l15] = f2bf(c1);
            }
            float pel = c0 * alv0 + c1 * alv1;
            float per = c0 * arv0 + c1 * arv1;
            pel += __shfl_xor(pel, 1); pel += __shfl_xor(pel, 2);
            pel += __shfl_xor(pel, 4); pel += __shfl_xor(pel, 8);
            per += __shfl_xor(per, 1); per += __shfl_xor(per, 2);
            per += __shfl_xor(per, 4); per += __shfl_xor(per, 8);
            if (l15 == 0 && row < n) {
                el[row * 4 + wave] = pel;
                er[row * 4 + wave] = per;
            }
        }
    }
}

// ---------------- agg core: quarter-wave per edge, lane owns 8 features (uint4 of bf16) ---------
static __device__ __forceinline__ void agg_core(
    int node, int lane, const int* __restrict__ offs, const u16* __restrict__ srcs,
    const float* __restrict__ el, const float* __restrict__ er, const u16* __restrict__ hf,
    float acc[8], float& den)
{
    int qw = lane >> 4;
    int q = lane & 15;
    int h = q >> 2;
    float erh = er[node * 4 + h];
    int beg = offs[node], end = offs[node + 1];
    den = 0.f;
#pragma unroll
    for (int i = 0; i < 8; i++) acc[i] = 0.f;
    int base = beg;
    for (; base + 8 <= end; base += 8) {
        int s0 = srcs[base + qw];
        int s1 = srcs[base + 4 + qw];
        float w0 = __expf(lrelu(el[s0 * 4 + h] + erh));
        float w1 = __expf(lrelu(el[s1 * 4 + h] + erh));
        uint4 u0 = *(const uint4*)(hf + (size_t)s0 * 128 + q * 8);
        uint4 u1 = *(const uint4*)(hf + (size_t)s1 * 128 + q * 8);
        den += w0 + w1;
        acc[0] += w0 * bflo(u0.x) + w1 * bflo(u1.x);
        acc[1] += w0 * bfhi(u0.x) + w1 * bfhi(u1.x);
        acc[2] += w0 * bflo(u0.y) + w1 * bflo(u1.y);
        acc[3] += w0 * bfhi(u0.y) + w1 * bfhi(u1.y);
        acc[4] += w0 * bflo(u0.z) + w1 * bflo(u1.z);
        acc[5] += w0 * bfhi(u0.z) + w1 * bfhi(u1.z);
        acc[6] += w0 * bflo(u0.w) + w1 * bflo(u1.w);
        acc[7] += w0 * bfhi(u0.w) + w1 * bfhi(u1.w);
    }
    for (; base < end; base += 4) {
        int e = base + qw;
        bool valid = e < end;
        int ec = valid ? e : end - 1;
        int s = srcs[ec];
        float w = valid ? __expf(lrelu(el[s * 4 + h] + erh)) : 0.f;
        uint4 u = *(const uint4*)(hf + (size_t)s * 128 + q * 8);
        den += w;
        acc[0] += w * bflo(u.x);
        acc[1] += w * bfhi(u.x);
        acc[2] += w * bflo(u.y);
        acc[3] += w * bfhi(u.y);
        acc[4] += w * bflo(u.z);
        acc[5] += w * bfhi(u.z);
        acc[6] += w * bflo(u.w);
        acc[7] += w * bfhi(u.w);
    }
#pragma unroll
    for (int i = 0; i < 8; i++) {
        acc[i] += __shfl_xor(acc[i], 16);
        acc[i] += __shfl_xor(acc[i], 32);
    }
    den += __shfl_xor(den, 16);
    den += __shfl_xor(den, 32);
}

// ---------------- layer-1 aggregation (relu, bf16 out) ----------------
__global__ __launch_bounds__(256) void agg1_k(const int* __restrict__ offs, const u16* __restrict__ srcs,
                                              const float* __restrict__ el, const float* __restrict__ er,
                                              const u16* __restrict__ hf, const float* __restrict__ bias,
                                              u16* __restrict__ h1) {
    int node = blockIdx.x * 4 + (threadIdx.x >> 6);
    int lane = threadIdx.x & 63;
    if (node >= N_NODES) return;
    float acc[8], den;
    agg_core(node, lane, offs, srcs, el, er, hf, acc, den);
    int qw = lane >> 4, q = lane & 15;
    if (qw == 0) {
        float inv = 1.0f / fmaxf(den, 1e-30f);
        float o[8];
#pragma unroll
        for (int i = 0; i < 8; i++)
            o[i] = fmaxf(acc[i] * inv + bias[q * 8 + i], 0.f);
        uint4 pk;
        pk.x = pack2(o[0], o[1]);
        pk.y = pack2(o[2], o[3]);
        pk.z = pack2(o[4], o[5]);
        pk.w = pack2(o[6], o[7]);
        *(uint4*)(h1 + (size_t)node * 128 + q * 8) = pk;
    }
}

// ---------------- layer-2 aggregation fused with head-mean/relu/proj/softmax ----------------
__global__ __launch_bounds__(256) void agg2_k(const int* __restrict__ offs, const u16* __restrict__ srcs,
                                              const float* __restrict__ el, const float* __restrict__ er,
                                              const u16* __restrict__ hf, const float* __restrict__ bias,
                                              const float* __restrict__ Wout, const float* __restrict__ bout,
                                              float2* __restrict__ out) {
    int node = blockIdx.x * 4 + (threadIdx.x >> 6);
    int lane = threadIdx.x & 63;
    if (node >= N_NODES) return;
    float acc[8], den;
    agg_core(node, lane, offs, srcs, el, er, hf, acc, den);
    int q = lane & 15;
    float inv = 1.0f / fmaxf(den, 1e-30f);
    float o[8];
#pragma unroll
    for (int i = 0; i < 8; i++) o[i] = acc[i] * inv + bias[q * 8 + i];
#pragma unroll
    for (int i = 0; i < 8; i++) {
        o[i] += __shfl_xor(o[i], 4);
        o[i] += __shfl_xor(o[i], 8);
        o[i] = fmaxf(0.25f * o[i], 0.f);
    }
    int d0 = (q & 3) * 8;
    float l0 = 0.f, l1 = 0.f;
#pragma unroll
    for (int i = 0; i < 8; i++) {
        l0 += o[i] * Wout[(d0 + i) * 2];
        l1 += o[i] * Wout[(d0 + i) * 2 + 1];
    }
    l0 += __shfl_xor(l0, 1); l0 += __shfl_xor(l0, 2);
    l1 += __shfl_xor(l1, 1); l1 += __shfl_xor(l1, 2);
    if (lane == 0) {
        l0 += bout[0];
        l1 += bout[1];
        float mx = fmaxf(l0, l1);
        float e0 = __expf(l0 - mx), e1 = __expf(l1 - mx);
        float invs = 1.f / (e0 + e1);
        out[node] = make_float2(e0 * invs, e1 * invs);
    }
}

extern "C" void kernel_launch(void* const* d_in, const int* in_sizes, int n_in,
                              void* d_out, int out_size, void* d_ws, size_t ws_size,
                              hipStream_t stream) {
    const float* in_feat = (const float*)d_in[0];
    const float* W1   = (const float*)d_in[1];
    const float* al1  = (const float*)d_in[2];
    const float* ar1  = (const float*)d_in[3];
    const float* b1   = (const float*)d_in[4];
    const float* W2   = (const float*)d_in[5];
    const float* al2  = (const float*)d_in[6];
    const float* ar2  = (const float*)d_in[7];
    const float* b2   = (const float*)d_in[8];
    const float* Wout = (const float*)d_in[9];
    const float* bout = (const float*)d_in[10];
    const int*   src  = (const int*)d_in[11];
    const int*   dst  = (const int*)d_in[12];
    float* out = (float*)d_out;

    char* ws = (char*)d_ws;
    size_t off = 0;
    auto carve = [&](size_t bytes) {
        char* p = ws + off;
        off = (off + bytes + 255) & ~(size_t)255;
        return p;
    };
    u16*   hfA      = (u16*)carve((size_t)N_NODES * 128 * 2);
    u16*   h1       = (u16*)carve((size_t)N_NODES * 128 * 2);
    float* el       = (float*)carve((size_t)N_NODES * 4 * 4);
    float* er       = (float*)carve((size_t)N_NODES * 4 * 4);
    u16*   srcs     = (u16*)carve((size_t)N_EDGES * 2);
    u32*   bucketed = (u32*)carve((size_t)N_EDGES * 4);
    u32*   bcnt     = (u32*)carve((size_t)NHB * NBUCK * 4);
    u32*   wbase    = (u32*)carve((size_t)NHB * NBUCK * 4);
    int*   bstart   = (int*)carve((size_t)(NBUCK + 1) * 4);
    int*   offs     = (int*)carve((size_t)(N_NODES + 1) * 4);
    u16*   Wp1      = (u16*)carve((size_t)16384 * 2);
    u16*   Wp2      = (u16*)carve((size_t)16384 * 2);
    (void)ws_size; (void)in_sizes; (void)n_in; (void)out_size;

    const int GB = (N_NODES + 63) / 64;          // 782
    const int AB = (N_NODES + 3) / 4;            // 12500

    // bucketed CSR build + weight pre-pack
    bhist_k<<<NHB, 1024, 0, stream>>>(dst, bcnt);
    packW_k<<<128, 256, 0, stream>>>(W1, W2, Wp1, Wp2);
    bscan_k<<<1, 256, 0, stream>>>(bcnt, wbase, bstart);
    bscatter_k<<<NHB, 1024, 0, stream>>>(src, dst, wbase, bstart, bucketed);
    bcsr_k<<<NBUCK, 256, 0, stream>>>(bucketed, bstart, offs, srcs);

    // layer 1
    gemm_mfma<0><<<GB, 256, 0, stream>>>(in_feat, Wp1, al1, ar1, hfA, el, er, N_NODES);
    agg1_k<<<AB, 256, 0, stream>>>(offs, srcs, el, er, hfA, b1, h1);

    // layer 2
    gemm_mfma<1><<<GB, 256, 0, stream>>>(h1, Wp2, al2, ar2, hfA, el, er, N_NODES);
    agg2_k<<<AB, 256, 0, stream>>>(offs, srcs, el, er, hfA, b2, Wout, bout, (float2*)out);
}

// Round 8
// 223.284 us; speedup vs baseline: 1.1710x; 1.1710x over previous
//
#include <hip/hip_runtime.h>
#include <cmath>

#define N_NODES 50000
#define N_EDGES 800000
#define NBUCK 196          // buckets of 256 nodes: bucket = dst >> 8
#define NHB 196            // histogram blocks, 4096 edges each
#define EPB 4096
// IN_DIM = HEADS*HID = 128, HEADS=4, HID=32

typedef unsigned short u16;
typedef unsigned int u32;
typedef __attribute__((ext_vector_type(8))) short bf16x8;
typedef __attribute__((ext_vector_type(4))) float f32x4;

static __device__ __forceinline__ float lrelu(float x) { return x > 0.f ? x : 0.2f * x; }
static __device__ __forceinline__ float bf2f(u16 u) { return __uint_as_float(((u32)u) << 16); }
static __device__ __forceinline__ float bflo(u32 u) { return __uint_as_float(u << 16); }
static __device__ __forceinline__ float bfhi(u32 u) { return __uint_as_float(u & 0xFFFF0000u); }
static __device__ __forceinline__ u16 f2bf(float f) {
    u32 b = __float_as_uint(f);
    return (u16)((b + 0x7FFFu + ((b >> 16) & 1u)) >> 16);  // RNE
}
static __device__ __forceinline__ u32 pack2(float a, float b) {
    return (u32)f2bf(a) | ((u32)f2bf(b) << 16);
}

// ---------------- bucketed CSR build ----------------
__global__ __launch_bounds__(1024) void bhist_k(const int* __restrict__ dst, u32* __restrict__ bcnt) {
    __shared__ u32 hist[NBUCK];
    int tid = threadIdx.x;
    for (int i = tid; i < NBUCK; i += 1024) hist[i] = 0;
    __syncthreads();
    int base = blockIdx.x * EPB;
#pragma unroll
    for (int k = 0; k < 4; ++k) {
        int e = base + k * 1024 + tid;
        if (e < N_EDGES) atomicAdd(&hist[dst[e] >> 8], 1u);
    }
    __syncthreads();
    for (int i = tid; i < NBUCK; i += 1024) bcnt[(size_t)blockIdx.x * NBUCK + i] = hist[i];
}

__global__ __launch_bounds__(256) void bscan_k(const u32* __restrict__ bcnt, u32* __restrict__ wbase,
                                               int* __restrict__ bstart) {
    __shared__ int s[256];
    int t = threadIdx.x;
    u32 run = 0;
    if (t < NBUCK) {
        for (int blk = 0; blk < NHB; ++blk) {
            u32 v = bcnt[(size_t)blk * NBUCK + t];
            wbase[(size_t)blk * NBUCK + t] = run;
            run += v;
        }
    }
    s[t] = (t < NBUCK) ? (int)run : 0;
    __syncthreads();
    for (int o = 1; o < 256; o <<= 1) {
        int v = (t >= o) ? s[t - o] : 0;
        __syncthreads();
        s[t] += v;
        __syncthreads();
    }
    if (t < NBUCK) bstart[t] = (t == 0) ? 0 : s[t - 1];
    if (t == NBUCK - 1) bstart[NBUCK] = s[t];
}

__global__ __launch_bounds__(1024) void bscatter_k(const int* __restrict__ src, const int* __restrict__ dst,
                                                   const u32* __restrict__ wbase, const int* __restrict__ bstart,
                                                   u32* __restrict__ bucketed) {
    __shared__ u32 pos[NBUCK];
    int tid = threadIdx.x;
    for (int i = tid; i < NBUCK; i += 1024)
        pos[i] = (u32)bstart[i] + wbase[(size_t)blockIdx.x * NBUCK + i];
    __syncthreads();
    int base = blockIdx.x * EPB;
#pragma unroll
    for (int k = 0; k < 4; ++k) {
        int e = base + k * 1024 + tid;
        if (e < N_EDGES) {
            int d = dst[e];
            int b = d >> 8;
            u32 p = atomicAdd(&pos[b], 1u);
            bucketed[p] = (u32)src[e] | ((u32)(d & 255) << 16);
        }
    }
}

// per-bucket fine CSR (R6 version — sort experiment reverted: 778K LDS conflicts, −41 µs)
__global__ __launch_bounds__(256) void bcsr_k(const u32* __restrict__ bucketed, const int* __restrict__ bstart,
                                              int* __restrict__ offs, u16* __restrict__ srcs) {
    __shared__ u32 cnt[256];
    __shared__ int s[256];
    __shared__ u32 fp[256];
    int b = blockIdx.x;
    int tid = threadIdx.x;
    int ebeg = bstart[b], eend = bstart[b + 1];
    int ne = eend - ebeg;
    cnt[tid] = 0;
    __syncthreads();
    for (int i = tid; i < ne; i += 256)
        atomicAdd(&cnt[bucketed[ebeg + i] >> 16], 1u);
    __syncthreads();
    s[tid] = (int)cnt[tid];
    __syncthreads();
    for (int o = 1; o < 256; o <<= 1) {
        int v = (tid >= o) ? s[tid - o] : 0;
        __syncthreads();
        s[tid] += v;
        __syncthreads();
    }
    int excl = s[tid] - (int)cnt[tid];
    int node = b * 256 + tid;
    if (node < N_NODES) offs[node] = ebeg + excl;
    if (b == NBUCK - 1 && tid == 0) offs[N_NODES] = N_EDGES;
    fp[tid] = (u32)excl;
    __syncthreads();
    for (int i = tid; i < ne; i += 256) {
        u32 u = bucketed[ebeg + i];
        u32 p = atomicAdd(&fp[u >> 16], 1u);
        srcs[ebeg + p] = (u16)(u & 0xFFFFu);
    }
}

// ---------------- W pre-pack: both layers in one dispatch ----------------
__global__ __launch_bounds__(256) void packW_k(const float* __restrict__ W1, const float* __restrict__ W2,
                                               u16* __restrict__ Wp1, u16* __restrict__ Wp2) {
    int gi = blockIdx.x * 256 + threadIdx.x;
    const float* W = (gi < 16384) ? W1 : W2;
    u16* Wp = (gi < 16384) ? Wp1 : Wp2;
    int i = gi & 16383;
    int j = i & 7, lane = (i >> 3) & 63, ks = (i >> 9) & 3, nt = i >> 11;
    int k = ks * 32 + (lane >> 4) * 8 + j;
    int ncol = nt * 16 + (lane & 15);
    Wp[i] = f2bf(W[k * 128 + ncol]);
}

// ---------------- MFMA GEMM (X[N,128] @ W[128,128]) fused with el/er head dots ----------------
template <int BF16IN>
__global__ __launch_bounds__(256) void gemm_mfma(
    const void* __restrict__ Xv, const u16* __restrict__ Wp,
    const float* __restrict__ al, const float* __restrict__ ar,
    u16* __restrict__ hf, float* __restrict__ el, float* __restrict__ er, int n)
{
    __shared__ u16 xs[64][136];   // +8 pad: row stride 272B -> 2-way LDS bank aliasing (free)
    int row0 = blockIdx.x * 64;
    int tid = threadIdx.x;
    if (BF16IN) {
        const uint4* Xb = (const uint4*)Xv;
        for (int i = tid; i < 1024; i += 256) {
            int r = i >> 4, c = i & 15;
            uint4 v = make_uint4(0u, 0u, 0u, 0u);
            if (row0 + r < n) v = Xb[(size_t)(row0 + r) * 16 + c];
            ((uint4*)&xs[r][0])[c] = v;
        }
    } else {
        const float4* X4 = (const float4*)Xv;
        for (int i = tid; i < 2048; i += 256) {
            int r = i >> 5, c = i & 31;
            float4 v = make_float4(0.f, 0.f, 0.f, 0.f);
            if (row0 + r < n) v = X4[(size_t)(row0 + r) * 32 + c];
            ((uint2*)&xs[r][0])[c] = make_uint2(pack2(v.x, v.y), pack2(v.z, v.w));
        }
    }
    __syncthreads();

    int wave = tid >> 6, lane = tid & 63;
    int quad = lane >> 4, l15 = lane & 15;

    bf16x8 bfrag[2][4];
#pragma unroll
    for (int ct = 0; ct < 2; ++ct) {
        int nt = wave * 2 + ct;
#pragma unroll
        for (int ks = 0; ks < 4; ++ks)
            bfrag[ct][ks] = *(const bf16x8*)(Wp + ((((nt * 4 + ks) * 64) + lane) << 3));
    }

    f32x4 acc[4][2];
#pragma unroll
    for (int rt = 0; rt < 4; ++rt)
#pragma unroll
        for (int ct = 0; ct < 2; ++ct)
            acc[rt][ct] = (f32x4){0.f, 0.f, 0.f, 0.f};

#pragma unroll
    for (int ks = 0; ks < 4; ++ks) {
#pragma unroll
        for (int rt = 0; rt < 4; ++rt) {
            bf16x8 a = *(const bf16x8*)&xs[rt * 16 + l15][ks * 32 + quad * 8];
            acc[rt][0] = __builtin_amdgcn_mfma_f32_16x16x32_bf16(a, bfrag[0][ks], acc[rt][0], 0, 0, 0);
            acc[rt][1] = __builtin_amdgcn_mfma_f32_16x16x32_bf16(a, bfrag[1][ks], acc[rt][1], 0, 0, 0);
        }
    }

    float alv0 = al[wave * 32 + l15], alv1 = al[wave * 32 + 16 + l15];
    float arv0 = ar[wave * 32 + l15], arv1 = ar[wave * 32 + 16 + l15];
#pragma unroll
    for (int rt = 0; rt < 4; ++rt) {
#pragma unroll
        for (int r = 0; r < 4; ++r) {
            int row = row0 + rt * 16 + quad * 4 + r;
            float c0 = acc[rt][0][r], c1 = acc[rt][1][r];
            if (row < n) {
                hf[(size_t)row * 128 + wave * 32 + l15] = f2bf(c0);
                hf[(size_t)row * 128 + wave * 32 + 16 + l15] = f2bf(c1);
            }
            float pel = c0 * alv0 + c1 * alv1;
            float per = c0 * arv0 + c1 * arv1;
            pel += __shfl_xor(pel, 1); pel += __shfl_xor(pel, 2);
            pel += __shfl_xor(pel, 4); pel += __shfl_xor(pel, 8);
            per += __shfl_xor(per, 1); per += __shfl_xor(per, 2);
            per += __shfl_xor(per, 4); per += __shfl_xor(per, 8);
            if (l15 == 0 && row < n) {
                el[row * 4 + wave] = pel;
                er[row * 4 + wave] = per;
            }
        }
    }
}

// ---------------- agg core: quarter-wave per edge, adjacency preloaded via one coalesced
// load + shfl broadcast (removes the srcs load from the gather chain); 4 independent
// el+hf chains in flight. deg>64 fallback keeps memory path (P(deg>64) ~ 1e-20, Poisson-16).
static __device__ __forceinline__ void agg_core(
    int node, int lane, const int* __restrict__ offs, const u16* __restrict__ srcs,
    const float* __restrict__ el, const float* __restrict__ er, const u16* __restrict__ hf,
    float acc[8], float& den)
{
    int qw = lane >> 4;
    int q = lane & 15;
    int h = q >> 2;
    float erh = er[node * 4 + h];
    int beg = offs[node], end = offs[node + 1];
    int deg = end - beg;
    den = 0.f;
#pragma unroll
    for (int i = 0; i < 8; i++) acc[i] = 0.f;

    if (deg <= 64) {
        int psrc = (lane < deg) ? (int)srcs[beg + lane] : 0;
        int base = beg;
        for (; base + 16 <= end; base += 16) {
            int j = base - beg + qw;
            int s0 = __shfl(psrc, j);
            int s1 = __shfl(psrc, j + 4);
            int s2 = __shfl(psrc, j + 8);
            int s3 = __shfl(psrc, j + 12);
            float e0 = el[s0 * 4 + h], e1 = el[s1 * 4 + h];
            float e2 = el[s2 * 4 + h], e3 = el[s3 * 4 + h];
            uint4 u0 = *(const uint4*)(hf + (size_t)s0 * 128 + q * 8);
            uint4 u1 = *(const uint4*)(hf + (size_t)s1 * 128 + q * 8);
            uint4 u2 = *(const uint4*)(hf + (size_t)s2 * 128 + q * 8);
            uint4 u3 = *(const uint4*)(hf + (size_t)s3 * 128 + q * 8);
            float w0 = __expf(lrelu(e0 + erh));
            float w1 = __expf(lrelu(e1 + erh));
            float w2 = __expf(lrelu(e2 + erh));
            float w3 = __expf(lrelu(e3 + erh));
            den += (w0 + w1) + (w2 + w3);
            acc[0] += w0 * bflo(u0.x) + w1 * bflo(u1.x) + w2 * bflo(u2.x) + w3 * bflo(u3.x);
            acc[1] += w0 * bfhi(u0.x) + w1 * bfhi(u1.x) + w2 * bfhi(u2.x) + w3 * bfhi(u3.x);
            acc[2] += w0 * bflo(u0.y) + w1 * bflo(u1.y) + w2 * bflo(u2.y) + w3 * bflo(u3.y);
            acc[3] += w0 * bfhi(u0.y) + w1 * bfhi(u1.y) + w2 * bfhi(u2.y) + w3 * bfhi(u3.y);
            acc[4] += w0 * bflo(u0.z) + w1 * bflo(u1.z) + w2 * bflo(u2.z) + w3 * bflo(u3.z);
            acc[5] += w0 * bfhi(u0.z) + w1 * bfhi(u1.z) + w2 * bfhi(u2.z) + w3 * bfhi(u3.z);
            acc[6] += w0 * bflo(u0.w) + w1 * bflo(u1.w) + w2 * bflo(u2.w) + w3 * bflo(u3.w);
            acc[7] += w0 * bfhi(u0.w) + w1 * bfhi(u1.w) + w2 * bfhi(u2.w) + w3 * bfhi(u3.w);
        }
        for (; base + 8 <= end; base += 8) {
            int j = base - beg + qw;
            int s0 = __shfl(psrc, j);
            int s1 = __shfl(psrc, j + 4);
            float e0 = el[s0 * 4 + h], e1 = el[s1 * 4 + h];
            uint4 u0 = *(const uint4*)(hf + (size_t)s0 * 128 + q * 8);
            uint4 u1 = *(const uint4*)(hf + (size_t)s1 * 128 + q * 8);
            float w0 = __expf(lrelu(e0 + erh));
            float w1 = __expf(lrelu(e1 + erh));
            den += w0 + w1;
            acc[0] += w0 * bflo(u0.x) + w1 * bflo(u1.x);
            acc[1] += w0 * bfhi(u0.x) + w1 * bfhi(u1.x);
            acc[2] += w0 * bflo(u0.y) + w1 * bflo(u1.y);
            acc[3] += w0 * bfhi(u0.y) + w1 * bfhi(u1.y);
            acc[4] += w0 * bflo(u0.z) + w1 * bflo(u1.z);
            acc[5] += w0 * bfhi(u0.z) + w1 * bfhi(u1.z);
            acc[6] += w0 * bflo(u0.w) + w1 * bflo(u1.w);
            acc[7] += w0 * bfhi(u0.w) + w1 * bfhi(u1.w);
        }
        for (; base < end; base += 4) {
            int e = base + qw;
            bool valid = e < end;
            int j = valid ? (e - beg) : 0;
            int s = __shfl(psrc, j);
            float w = valid ? __expf(lrelu(el[s * 4 + h] + erh)) : 0.f;
            uint4 u = *(const uint4*)(hf + (size_t)s * 128 + q * 8);
            den += w;
            acc[0] += w * bflo(u.x);
            acc[1] += w * bfhi(u.x);
            acc[2] += w * bflo(u.y);
            acc[3] += w * bfhi(u.y);
            acc[4] += w * bflo(u.z);
            acc[5] += w * bfhi(u.z);
            acc[6] += w * bflo(u.w);
            acc[7] += w * bfhi(u.w);
        }
    } else {
        int base = beg;
        for (; base + 8 <= end; base += 8) {
            int s0 = srcs[base + qw];
            int s1 = srcs[base + 4 + qw];
            float w0 = __expf(lrelu(el[s0 * 4 + h] + erh));
            float w1 = __expf(lrelu(el[s1 * 4 + h] + erh));
            uint4 u0 = *(const uint4*)(hf + (size_t)s0 * 128 + q * 8);
            uint4 u1 = *(const uint4*)(hf + (size_t)s1 * 128 + q * 8);
            den += w0 + w1;
            acc[0] += w0 * bflo(u0.x) + w1 * bflo(u1.x);
            acc[1] += w0 * bfhi(u0.x) + w1 * bfhi(u1.x);
            acc[2] += w0 * bflo(u0.y) + w1 * bflo(u1.y);
            acc[3] += w0 * bfhi(u0.y) + w1 * bfhi(u1.y);
            acc[4] += w0 * bflo(u0.z) + w1 * bflo(u1.z);
            acc[5] += w0 * bfhi(u0.z) + w1 * bfhi(u1.z);
            acc[6] += w0 * bflo(u0.w) + w1 * bflo(u1.w);
            acc[7] += w0 * bfhi(u0.w) + w1 * bfhi(u1.w);
        }
        for (; base < end; base += 4) {
            int e = base + qw;
            bool valid = e < end;
            int ec = valid ? e : end - 1;
            int s = srcs[ec];
            float w = valid ? __expf(lrelu(el[s * 4 + h] + erh)) : 0.f;
            uint4 u = *(const uint4*)(hf + (size_t)s * 128 + q * 8);
            den += w;
            acc[0] += w * bflo(u.x);
            acc[1] += w * bfhi(u.x);
            acc[2] += w * bflo(u.y);
            acc[3] += w * bfhi(u.y);
            acc[4] += w * bflo(u.z);
            acc[5] += w * bfhi(u.z);
            acc[6] += w * bflo(u.w);
            acc[7] += w * bfhi(u.w);
        }
    }
#pragma unroll
    for (int i = 0; i < 8; i++) {
        acc[i] += __shfl_xor(acc[i], 16);
        acc[i] += __shfl_xor(acc[i], 32);
    }
    den += __shfl_xor(den, 16);
    den += __shfl_xor(den, 32);
}

// ---------------- layer-1 aggregation (relu, bf16 out) ----------------
__global__ __launch_bounds__(256) void agg1_k(const int* __restrict__ offs, const u16* __restrict__ srcs,
                                              const float* __restrict__ el, const float* __restrict__ er,
                                              const u16* __restrict__ hf, const float* __restrict__ bias,
                                              u16* __restrict__ h1) {
    int node = blockIdx.x * 4 + (threadIdx.x >> 6);
    int lane = threadIdx.x & 63;
    if (node >= N_NODES) return;
    float acc[8], den;
    agg_core(node, lane, offs, srcs, el, er, hf, acc, den);
    int qw = lane >> 4, q = lane & 15;
    if (qw == 0) {
        float inv = 1.0f / fmaxf(den, 1e-30f);
        float o[8];
#pragma unroll
        for (int i = 0; i < 8; i++)
            o[i] = fmaxf(acc[i] * inv + bias[q * 8 + i], 0.f);
        uint4 pk;
        pk.x = pack2(o[0], o[1]);
        pk.y = pack2(o[2], o[3]);
        pk.z = pack2(o[4], o[5]);
        pk.w = pack2(o[6], o[7]);
        *(uint4*)(h1 + (size_t)node * 128 + q * 8) = pk;
    }
}

// ---------------- layer-2 aggregation fused with head-mean/relu/proj/softmax ----------------
__global__ __launch_bounds__(256) void agg2_k(const int* __restrict__ offs, const u16* __restrict__ srcs,
                                              const float* __restrict__ el, const float* __restrict__ er,
                                              const u16* __restrict__ hf, const float* __restrict__ bias,
                                              const float* __restrict__ Wout, const float* __restrict__ bout,
                                              float2* __restrict__ out) {
    int node = blockIdx.x * 4 + (threadIdx.x >> 6);
    int lane = threadIdx.x & 63;
    if (node >= N_NODES) return;
    float acc[8], den;
    agg_core(node, lane, offs, srcs, el, er, hf, acc, den);
    int q = lane & 15;
    float inv = 1.0f / fmaxf(den, 1e-30f);
    float o[8];
#pragma unroll
    for (int i = 0; i < 8; i++) o[i] = acc[i] * inv + bias[q * 8 + i];
#pragma unroll
    for (int i = 0; i < 8; i++) {
        o[i] += __shfl_xor(o[i], 4);
        o[i] += __shfl_xor(o[i], 8);
        o[i] = fmaxf(0.25f * o[i], 0.f);
    }
    int d0 = (q & 3) * 8;
    float l0 = 0.f, l1 = 0.f;
#pragma unroll
    for (int i = 0; i < 8; i++) {
        l0 += o[i] * Wout[(d0 + i) * 2];
        l1 += o[i] * Wout[(d0 + i) * 2 + 1];
    }
    l0 += __shfl_xor(l0, 1); l0 += __shfl_xor(l0, 2);
    l1 += __shfl_xor(l1, 1); l1 += __shfl_xor(l1, 2);
    if (lane == 0) {
        l0 += bout[0];
        l1 += bout[1];
        float mx = fmaxf(l0, l1);
        float e0 = __expf(l0 - mx), e1 = __expf(l1 - mx);
        float invs = 1.f / (e0 + e1);
        out[node] = make_float2(e0 * invs, e1 * invs);
    }
}

extern "C" void kernel_launch(void* const* d_in, const int* in_sizes, int n_in,
                              void* d_out, int out_size, void* d_ws, size_t ws_size,
                              hipStream_t stream) {
    const float* in_feat = (const float*)d_in[0];
    const float* W1   = (const float*)d_in[1];
    const float* al1  = (const float*)d_in[2];
    const float* ar1  = (const float*)d_in[3];
    const float* b1   = (const float*)d_in[4];
    const float* W2   = (const float*)d_in[5];
    const float* al2  = (const float*)d_in[6];
    const float* ar2  = (const float*)d_in[7];
    const float* b2   = (const float*)d_in[8];
    const float* Wout = (const float*)d_in[9];
    const float* bout = (const float*)d_in[10];
    const int*   src  = (const int*)d_in[11];
    const int*   dst  = (const int*)d_in[12];
    float* out = (float*)d_out;

    char* ws = (char*)d_ws;
    size_t off = 0;
    auto carve = [&](size_t bytes) {
        char* p = ws + off;
        off = (off + bytes + 255) & ~(size_t)255;
        return p;
    };
    u16*   hfA      = (u16*)carve((size_t)N_NODES * 128 * 2);
    u16*   h1       = (u16*)carve((size_t)N_NODES * 128 * 2);
    float* el       = (float*)carve((size_t)N_NODES * 4 * 4);
    float* er       = (float*)carve((size_t)N_NODES * 4 * 4);
    u16*   srcs     = (u16*)carve((size_t)N_EDGES * 2);
    u32*   bucketed = (u32*)carve((size_t)N_EDGES * 4);
    u32*   bcnt     = (u32*)carve((size_t)NHB * NBUCK * 4);
    u32*   wbase    = (u32*)carve((size_t)NHB * NBUCK * 4);
    int*   bstart   = (int*)carve((size_t)(NBUCK + 1) * 4);
    int*   offs     = (int*)carve((size_t)(N_NODES + 1) * 4);
    u16*   Wp1      = (u16*)carve((size_t)16384 * 2);
    u16*   Wp2      = (u16*)carve((size_t)16384 * 2);
    (void)ws_size; (void)in_sizes; (void)n_in; (void)out_size;

    const int GB = (N_NODES + 63) / 64;          // 782
    const int AB = (N_NODES + 3) / 4;            // 12500

    // bucketed CSR build + weight pre-pack
    bhist_k<<<NHB, 1024, 0, stream>>>(dst, bcnt);
    packW_k<<<128, 256, 0, stream>>>(W1, W2, Wp1, Wp2);
    bscan_k<<<1, 256, 0, stream>>>(bcnt, wbase, bstart);
    bscatter_k<<<NHB, 1024, 0, stream>>>(src, dst, wbase, bstart, bucketed);
    bcsr_k<<<NBUCK, 256, 0, stream>>>(bucketed, bstart, offs, srcs);

    // layer 1
    gemm_mfma<0><<<GB, 256, 0, stream>>>(in_feat, Wp1, al1, ar1, hfA, el, er, N_NODES);
    agg1_k<<<AB, 256, 0, stream>>>(offs, srcs, el, er, hfA, b1, h1);

    // layer 2
    gemm_mfma<1><<<GB, 256, 0, stream>>>(h1, Wp2, al2, ar2, hfA, el, er, N_NODES);
    agg2_k<<<AB, 256, 0, stream>>>(offs, srcs, el, er, hfA, b2, Wout, bout, (float2*)out);
}